// Round 10
// baseline (201.457 us; speedup 1.0000x reference)
//
#include <hip/hip_runtime.h>

#define NB 8
#define NC 256
#define IMG 3600
#define MP 3584         // M padded (multiple of 128)
#define NRB 28          // MP/128 row/col tiles
#define NKB 8           // NC/32 K-tiles of 32
#define SCALE 0.28853901f   // 0.2 * log2(e): exp(0.2*dot) = exp2(SCALE*dot)
#define LN2X2 1.38629436f   // 2*ln2: dist_diag term

typedef unsigned short u16;
typedef __bf16 bf16x8 __attribute__((ext_vector_type(8)));
typedef float  f32x4  __attribute__((ext_vector_type(4)));
typedef unsigned short u16x8 __attribute__((ext_vector_type(8)));

__device__ __forceinline__ u16 f2bf(float f) {
  unsigned u = __builtin_bit_cast(unsigned, f);
  u += 0x7FFFu + ((u >> 16) & 1u);          // round-to-nearest-even
  return (u16)(u >> 16);
}

__device__ __forceinline__ void gld16(const void* g, void* l) {
  __builtin_amdgcn_global_load_lds(
      (__attribute__((address_space(1))) void*)g,
      (__attribute__((address_space(3))) void*)l, 16, 0, 0);
}

// ---------------------------------------------------------------------------
// Gather v3 (unchanged, proven): LDS-staged transpose, both sides coalesced,
// XCD-aligned 1-D grid (id%8 == b), slot-swizzled tile layout
// slot = ch ^ ((row>>1)&3), folds row/col-sum + out zeroing.
// Rows >= M zero-filled (pad correction applied exactly in finalize).
// ---------------------------------------------------------------------------
__global__ __launch_bounds__(256)
void gather_kernel(const float* __restrict__ p1, const float* __restrict__ p2,
                   const int* __restrict__ y1, const int* __restrict__ x1,
                   const int* __restrict__ y2, const int* __restrict__ x2,
                   u16* __restrict__ des1, u16* __restrict__ des2,
                   float* __restrict__ zbase, float* __restrict__ out, int M) {
  __shared__ __align__(16) u16 tile[4096];   // 8 KB: 128 rows x 4 slots x 16B
  const int id = blockIdx.x;
  const int b = id & 7;                      // XCD = id%8 = b (matches reader)
  const int r = id >> 3;
  const int rb = r % NRB;
  const int r2 = r / NRB;
  const int kb = r2 % NKB;
  const int which = r2 / NKB;                // 0 -> des1 (A), 1 -> des2 (B)
  const float* P = (which ? p2 : p1) + (size_t)b * NC * IMG;
  const int* Y = which ? y2 : y1;
  const int* X = which ? x2 : x1;
  u16* D = which ? des2 : des1;
  const float sc = which ? 1.f : SCALE;      // A side pre-scaled by SCALE

  const int t = threadIdx.x;

  // fold zeroing of row_sum+col_sum (2*NB*MP contiguous floats) and out
  {
    const int gi = id * 256 + t;
    if (gi < 2 * NB * MP) zbase[gi] = 0.f;
    if (gi == 0) *out = 0.f;
  }

  const int row = t & 127, h = t >> 7;       // h selects chunks 2h, 2h+1
  const int m = rb * 128 + row;
  const bool mv = m < M;
  const int pix = mv ? (Y[m] * 60 + X[m]) : 0;
  const float* src = P + (size_t)(kb * 32 + h * 16) * IMG + pix;

  float v[16];                               // 16 c-planes, each wave-coalesced
#pragma unroll
  for (int j = 0; j < 16; ++j) v[j] = mv ? src[(size_t)j * IMG] : 0.f;

  u16x8 lo, hi;
#pragma unroll
  for (int j = 0; j < 8; ++j) lo[j] = f2bf(v[j] * sc);
#pragma unroll
  for (int j = 0; j < 8; ++j) hi[j] = f2bf(v[8 + j] * sc);

  const int sw = (row >> 1) & 3;
  *(u16x8*)&tile[((row * 4) + ((2 * h)     ^ sw)) * 8] = lo;
  *(u16x8*)&tile[((row * 4) + ((2 * h + 1) ^ sw)) * 8] = hi;
  __syncthreads();

  // linear LDS -> linear global: 2 x (64 lanes x 16B contiguous) per wave
  u16* Dt = D + (((size_t)b * NKB + kb) * NRB + rb) * 4096;
  *(u16x8*)(Dt + t * 8)         = *(const u16x8*)&tile[t * 8];
  *(u16x8*)(Dt + (t + 256) * 8) = *(const u16x8*)&tile[(t + 256) * 8];
}

// ---------------------------------------------------------------------------
// MFMA GEMM + fused exp2 / row / col / diag.
// v11 = CONSOLIDATION on spill-proof sync (R9 post-mortem).
//   R8/R9 failures diagnosed: hand-counted vmcnt(6/4) miscounts if the
//   register allocator (sitting at exactly the 128-reg cap) inserts scratch
//   VMEM ops; a functionally-neutral source change (nt formula) perturbed
//   codegen and flipped v8's lucky fit into a spilling, racing build.
//   Fix: NO counted waitcnts anywhere. Per iter, at the TOP:
//     vmcnt(0)   -- drains stage(kb)+loadB(kb), issued a FULL iteration ago
//                   (cheap), and is correct regardless of any compiler-
//                   inserted VMEM (spill-proof);
//     lgkmcnt(0) -- prev iter's frag ds_reads done (also spill-proof);
//     s_barrier  -- all waves agree;
//   then issue stage(kb+1)/loadB(kb+1) (prefetch gets a full iteration of
//   MFMA work to complete under), then ds_read A frags + 16 MFMAs.
//   WAR on bufA[(kb+1)&1]: last read at kb-1; every wave's lgkmcnt(0) at top
//   of kb precedes barrier(kb), and stage(kb+1) issues after barrier(kb). ✓
//   RAW on bufA[kb&1]: vmcnt(0)+barrier at top of kb. ✓  All hardware-
//   enforced; no inference chains, no counts.  (This is v6's proven scheme,
//   which passed, applied to the halved-LDS structure.)
// Structure (v8, passed): B direct L2->VGPR (flatmm addressing: offB =
//   row*64+slot*16, slot i-invariant, each load = one contiguous 1KB block),
//   double-buffered in regs; A gld16->LDS 2x8KB double buffer, frags
//   STREAMED through one 4-reg temp. Ordering: v8's stagger (the passing
//   one) -- the mt/nt reorder experiment is retired until its codegen
//   interaction is understood.
//   Registers ~115 unified < 128 cap (launch_bounds(256,4)) with SLACK ->
//   16 waves/CU and headroom against allocator drift. LDS 16KB.
//   kb loop fully unrolled (register subscripts compile-time).
// Lean epilogue unchanged (verified): bare exp2, no masks, pad handled in
// finalize. Frag layouts (16x16x32 bf16): A/B[row=l15][k=quad*8+j]; C/D
// col=l15, row=quad*4+reg. b=flat&7 -> XCD-pinned L2 set.
// ---------------------------------------------------------------------------
__global__ __launch_bounds__(256, 4)
void mfma_lse(const u16* __restrict__ des1, const u16* __restrict__ des2,
              float* __restrict__ row_sum, float* __restrict__ col_sum,
              float* __restrict__ diag, int M) {
  __shared__ __align__(16) u16 bufA[2][4096];   // 8 KB each, 16 KB total

  const int flat = blockIdx.x;
  const int b = flat & 7;
  const int f = flat >> 3;
  const int mt = f % NRB;
  const int nt = (f / NRB + mt) % NRB;          // v8's proven stagger
  const int m0 = mt * 128, n0 = nt * 128;
  const int t = threadIdx.x;
  const int w = t >> 6, lane = t & 63;
  const int wm = w >> 1, wn = w & 1;
  const int quad = lane >> 4, l15 = lane & 15;

  // ---- A: global -> LDS staging (2 gld16/thread per step) ----
  auto stage = [&](int kb, int sel) {
    const u16* Ak = des1 + (((size_t)b * NKB + kb) * NRB + mt) * 4096;
#pragma unroll
    for (int i = 0; i < 2; ++i) {
      int idx = i * 256 + t;
      gld16(Ak + (size_t)idx * 8, &bufA[sel][idx * 8]);
    }
  };

  // ---- B: global -> VGPR fragments (v5-proven addressing) ----
  const int rbw = wn * 64 + l15;
  const int offB = rbw * 64 + (quad ^ ((rbw >> 1) & 3)) * 16;  // bytes
  const char* Bbase =
      (const char*)(des2 + (((size_t)b * NKB) * NRB + nt) * 4096) + offB;
  const size_t kstride = (size_t)NRB * 4096 * sizeof(u16);     // bytes per kb

  bf16x8 bfr[2][4];
  auto loadB = [&](int kb, int sel) {
    const char* Bk = Bbase + (size_t)kb * kstride;
#pragma unroll
    for (int j = 0; j < 4; ++j)
      bfr[sel][j] = *(const bf16x8*)(Bk + j * 1024);
  };

  // per-lane A-frag LDS byte offset (slot is i-invariant: (16i)>>1 ≡ 0 mod 4)
  const int rowA = wm * 64 + l15;
  const int offA = rowA * 64 + (quad ^ ((rowA >> 1) & 3)) * 16;  // bytes

  f32x4 acc[4][4] = {};

  stage(0, 0);
  loadB(0, 0);
#pragma unroll
  for (int kb = 0; kb < NKB; ++kb) {
    asm volatile("s_waitcnt vmcnt(0)" ::: "memory");    // stage/loadB(kb) done
    asm volatile("s_waitcnt lgkmcnt(0)" ::: "memory");  // prev frag reads done
    asm volatile("s_barrier" ::: "memory");
    if (kb + 1 < NKB) {                                 // prefetch next step:
      stage(kb + 1, (kb + 1) & 1);                      // full iter to land
      loadB(kb + 1, (kb + 1) & 1);
    }

    const char* As = (const char*)bufA[kb & 1] + offA;
    const int s = kb & 1;
#pragma unroll
    for (int i = 0; i < 4; ++i) {
      bf16x8 af = *(const bf16x8*)(As + i * 1024);      // stream A frag i
#pragma unroll
      for (int j = 0; j < 4; ++j)
        acc[i][j] = __builtin_amdgcn_mfma_f32_16x16x32_bf16(
            af, bfr[s][j], acc[i][j], 0, 0, 0);
    }
  }

  // ---- lean epilogue: bare exp2, no masks, shuffle-reduced atomics ----
  float cp[4] = {0.f, 0.f, 0.f, 0.f};
#pragma unroll
  for (int i = 0; i < 4; ++i)
#pragma unroll
    for (int r = 0; r < 4; ++r) {
      float rv = 0.f;
#pragma unroll
      for (int j = 0; j < 4; ++j) {
        float e = exp2f(acc[i][j][r]);
        rv += e;
        cp[j] += e;
      }
      rv += __shfl_xor(rv, 1); rv += __shfl_xor(rv, 2);
      rv += __shfl_xor(rv, 4); rv += __shfl_xor(rv, 8);
      if (l15 == 0)
        atomicAdd(&row_sum[(size_t)b * MP + m0 + wm * 64 + i * 16 + quad * 4 + r], rv);
    }
#pragma unroll
  for (int j = 0; j < 4; ++j) {
    float c = cp[j];
    c += __shfl_xor(c, 16); c += __shfl_xor(c, 32);
    if (quad == 0)
      atomicAdd(&col_sum[(size_t)b * MP + n0 + wn * 64 + j * 16 + l15], c);
  }
  if (mt == nt && wm == wn) {
#pragma unroll
    for (int i = 0; i < 4; ++i)
#pragma unroll
      for (int r = 0; r < 4; ++r)
        if (l15 == quad * 4 + r)
          diag[(size_t)b * MP + m0 + wm * 64 + i * 16 + quad * 4 + r] =
              acc[i][i][r];
  }
}

// ---------------------------------------------------------------------------
// loss = mean over valid of log(rs - pad) + log(cs - pad) - 2*ln2*diag'
// pad = MP - M exact (pad rows/cols contributed exp2(0)=1 each).
// ---------------------------------------------------------------------------
__global__ __launch_bounds__(256)
void finalize(const float* __restrict__ row_sum, const float* __restrict__ col_sum,
              const float* __restrict__ diag, float* __restrict__ out,
              int M, float padf, float inv_total) {
  __shared__ float red[4];
  const int i = blockIdx.x * 256 + threadIdx.x;   // over NB*MP
  const int mm = i % MP;
  float s = 0.f;
  if (mm < M)
    s = __logf(row_sum[i] - padf) + __logf(col_sum[i] - padf) - LN2X2 * diag[i];
#pragma unroll
  for (int o = 1; o < 64; o <<= 1) s += __shfl_xor(s, o);
  const int lane = threadIdx.x & 63, wid = threadIdx.x >> 6;
  if (lane == 0) red[wid] = s;
  __syncthreads();
  if (threadIdx.x == 0)
    atomicAdd(out, (red[0] + red[1] + red[2] + red[3]) * inv_total);
}

extern "C" void kernel_launch(void* const* d_in, const int* in_sizes, int n_in,
                              void* d_out, int out_size, void* d_ws, size_t ws_size,
                              hipStream_t stream) {
  const float* p1 = (const float*)d_in[0];
  const float* p2 = (const float*)d_in[1];
  const int* y1 = (const int*)d_in[2];
  const int* x1 = (const int*)d_in[3];
  const int* y2 = (const int*)d_in[4];
  const int* x2 = (const int*)d_in[5];
  const int M = in_sizes[2];                    // 3540 (<= MP)

  float* row_sum = (float*)d_ws;                // NB*MP
  float* col_sum = row_sum + (size_t)NB * MP;   // NB*MP
  float* diagbuf = col_sum + (size_t)NB * MP;   // NB*MP
  size_t off = (((size_t)3 * NB * MP * sizeof(float)) + 255) & ~(size_t)255;
  u16* des1 = (u16*)((char*)d_ws + off);        // NB*MP*NC bf16, tiled+swizzled
  u16* des2 = des1 + (size_t)NB * MP * NC;

  // zeroing of row/col sums + out folded into gather_kernel (fewer graph nodes)
  // 1-D grid: id%8 == b -> gather writes des[b] on the XCD that reads it
  gather_kernel<<<dim3(2 * NKB * NRB * 8), 256, 0, stream>>>(
      p1, p2, y1, x1, y2, x2, des1, des2, row_sum, (float*)d_out, M);

  mfma_lse<<<dim3(NB * NRB * NRB), 256, 0, stream>>>(des1, des2, row_sum,
                                                     col_sum, diagbuf, M);

  finalize<<<(NB * MP) / 256, 256, 0, stream>>>(row_sum, col_sum, diagbuf,
                                                (float*)d_out, M,
                                                (float)(MP - M),
                                                1.f / (float)(NB * M));
}

// Round 12
// 178.321 us; speedup vs baseline: 1.1297x; 1.1297x over previous
//
#include <hip/hip_runtime.h>

#define NB 8
#define NC 256
#define IMG 3600
#define MP 3584         // M padded (multiple of 128)
#define NRB 28          // MP/128 row/col tiles
#define NKB 8           // NC/32 K-tiles of 32
#define SCALE 0.28853901f   // 0.2 * log2(e): exp(0.2*dot) = exp2(SCALE*dot)
#define LN2X2 1.38629436f   // 2*ln2: dist_diag term

typedef unsigned short u16;
typedef __bf16 bf16x8 __attribute__((ext_vector_type(8)));
typedef float  f32x4  __attribute__((ext_vector_type(4)));
typedef unsigned short u16x8 __attribute__((ext_vector_type(8)));

__device__ __forceinline__ u16 f2bf(float f) {
  unsigned u = __builtin_bit_cast(unsigned, f);
  u += 0x7FFFu + ((u >> 16) & 1u);          // round-to-nearest-even
  return (u16)(u >> 16);
}

__device__ __forceinline__ void gld16(const void* g, void* l) {
  __builtin_amdgcn_global_load_lds(
      (__attribute__((address_space(1))) void*)g,
      (__attribute__((address_space(3))) void*)l, 16, 0, 0);
}

// ---------------------------------------------------------------------------
// Gather v3 (unchanged from R5): LDS-staged transpose, both sides coalesced,
// XCD-aligned 1-D grid (id%8 == b), slot-swizzled tile layout
// slot = ch ^ ((row>>1)&3), folds row/col-sum + out zeroing.
// Rows >= M zero-filled (pad correction applied exactly in finalize).
// ---------------------------------------------------------------------------
__global__ __launch_bounds__(256)
void gather_kernel(const float* __restrict__ p1, const float* __restrict__ p2,
                   const int* __restrict__ y1, const int* __restrict__ x1,
                   const int* __restrict__ y2, const int* __restrict__ x2,
                   u16* __restrict__ des1, u16* __restrict__ des2,
                   float* __restrict__ zbase, float* __restrict__ out, int M) {
  __shared__ __align__(16) u16 tile[4096];   // 8 KB: 128 rows x 4 slots x 16B
  const int id = blockIdx.x;
  const int b = id & 7;                      // XCD = id%8 = b (matches reader)
  const int r = id >> 3;
  const int rb = r % NRB;
  const int r2 = r / NRB;
  const int kb = r2 % NKB;
  const int which = r2 / NKB;                // 0 -> des1 (A), 1 -> des2 (B)
  const float* P = (which ? p2 : p1) + (size_t)b * NC * IMG;
  const int* Y = which ? y2 : y1;
  const int* X = which ? x2 : x1;
  u16* D = which ? des2 : des1;
  const float sc = which ? 1.f : SCALE;      // A side pre-scaled by SCALE

  const int t = threadIdx.x;

  // fold zeroing of row_sum+col_sum (2*NB*MP contiguous floats) and out
  {
    const int gi = id * 256 + t;
    if (gi < 2 * NB * MP) zbase[gi] = 0.f;
    if (gi == 0) *out = 0.f;
  }

  const int row = t & 127, h = t >> 7;       // h selects chunks 2h, 2h+1
  const int m = rb * 128 + row;
  const bool mv = m < M;
  const int pix = mv ? (Y[m] * 60 + X[m]) : 0;
  const float* src = P + (size_t)(kb * 32 + h * 16) * IMG + pix;

  float v[16];                               // 16 c-planes, each wave-coalesced
#pragma unroll
  for (int j = 0; j < 16; ++j) v[j] = mv ? src[(size_t)j * IMG] : 0.f;

  u16x8 lo, hi;
#pragma unroll
  for (int j = 0; j < 8; ++j) lo[j] = f2bf(v[j] * sc);
#pragma unroll
  for (int j = 0; j < 8; ++j) hi[j] = f2bf(v[8 + j] * sc);

  const int sw = (row >> 1) & 3;
  *(u16x8*)&tile[((row * 4) + ((2 * h)     ^ sw)) * 8] = lo;
  *(u16x8*)&tile[((row * 4) + ((2 * h + 1) ^ sw)) * 8] = hi;
  __syncthreads();

  // linear LDS -> linear global: 2 x (64 lanes x 16B contiguous) per wave
  u16* Dt = D + (((size_t)b * NKB + kb) * NRB + rb) * 4096;
  *(u16x8*)(Dt + t * 8)         = *(const u16x8*)&tile[t * 8];
  *(u16x8*)(Dt + (t + 256) * 8) = *(const u16x8*)&tile[(t + 256) * 8];
}

// ---------------------------------------------------------------------------
// MFMA GEMM + fused exp2 / row / col / diag.
// v8: HALVE THE LDS PIPE (R6 model: 128 ds_read_b128/CU-step = 1536 cyc
// serialized through one LDS unit is the binding term).
//   * B side NEVER touches LDS: fragments load directly from L2 into VGPRs
//     (v5's proven flatmm addressing: offB = row*64 + slot*16 with slot
//     i-invariant -> each load's 64 lanes cover one contiguous 1KB block),
//     register double-buffered one K-step ahead. The 2x B duplication
//     between wm=0/1 waves is ~100 cyc apart on an 8KB working set -> L1.
//   * A side stays gld16->LDS (shared by both wn waves) but fragments are
//     STREAMED through one 4-reg temp (read af_i -> 4 MFMAs -> reuse),
//     freeing 12 regs to pay for the B double-buffer.
//   * 3-buffer A + SINGLE barrier per K-step with EARLY prefetch:
//     iter k: stage(k+1)->bufA[(k+1)%3] (2 gld16) + loadB(k+1)->bfr[(k+1)&1]
//     issued at top -> s_waitcnt vmcnt(6) (drains stage(k)'s 2 + B(k)'s 4;
//     the 6 just-issued stay in flight; never vmcnt(0) until last iter) ->
//     s_barrier -> {ds_read af_i; 4 MFMA} x4.
//     WAR-safe: bufA[(k+1)%3] was last read at step k-2; those reads were
//     consumed by MFMA(k-2) (compiler lgkm) before every wave arrived at
//     barrier(k-1), which I passed before this issue. RAW-safe: each wave's
//     vmcnt(6) precedes its barrier arrival -> post-barrier the A tile is
//     complete and own B regs are ready.
//   NOTE (R10 consolidation): this exact source measured 84us / no spill
//   (WRITE 75MB) in R7. The structure sits at the 128-unified-reg cap and is
//   codegen-sensitive: functionally-neutral edits (R8/R9) perturbed the
//   allocator into spilling, which invalidates the hand-counted vmcnt ->
//   NaN. Resubmitted BYTE-IDENTICAL to reproduce the passing binary. Any
//   future change must first buy register slack (e.g. single-buffer bfr).
//   Registers: acc 64 + bfr 32 + af 4 + addressing ~20 = ~120 unified;
//   __launch_bounds__(256,4) caps at 128 -> 16 waves/CU (the occupancy all
//   7 rounds agree is mandatory). LDS 3x8KB = 24KB. kb loop fully unrolled
//   (register-array subscripts compile-time; rule #20).
// Lean epilogue unchanged (verified): bare exp2, no masks, pad handled in
// finalize. Frag layouts (16x16x32 bf16): A/B[row=l15][k=quad*8+j]; C/D
// col=l15, row=quad*4+reg. batch = blockIdx&7 -> XCD-pinned L2 set.
// ---------------------------------------------------------------------------
__global__ __launch_bounds__(256, 4)
void mfma_lse(const u16* __restrict__ des1, const u16* __restrict__ des2,
              float* __restrict__ row_sum, float* __restrict__ col_sum,
              float* __restrict__ diag, int M) {
  __shared__ __align__(16) u16 bufA[3][4096];   // 8 KB each, 24 KB total

  const int flat = blockIdx.x;
  const int b = flat & 7;
  const int f = flat >> 3;
  const int mt = f % NRB;
  const int nt = (f / NRB + mt) % NRB;          // stagger col-atomic order
  const int m0 = mt * 128, n0 = nt * 128;
  const int t = threadIdx.x;
  const int w = t >> 6, lane = t & 63;
  const int wm = w >> 1, wn = w & 1;
  const int quad = lane >> 4, l15 = lane & 15;

  // ---- A: global -> LDS staging (2 gld16/thread per step) ----
  auto stage = [&](int kb, int sel) {
    const u16* Ak = des1 + (((size_t)b * NKB + kb) * NRB + mt) * 4096;
#pragma unroll
    for (int i = 0; i < 2; ++i) {
      int idx = i * 256 + t;
      gld16(Ak + (size_t)idx * 8, &bufA[sel][idx * 8]);
    }
  };

  // ---- B: global -> VGPR fragments (v5-proven addressing) ----
  const int rbw = wn * 64 + l15;
  const int offB = rbw * 64 + (quad ^ ((rbw >> 1) & 3)) * 16;  // bytes
  const char* Bbase =
      (const char*)(des2 + (((size_t)b * NKB) * NRB + nt) * 4096) + offB;
  const size_t kstride = (size_t)NRB * 4096 * sizeof(u16);     // bytes per kb

  bf16x8 bfr[2][4];
  auto loadB = [&](int kb, int sel) {
    const char* Bk = Bbase + (size_t)kb * kstride;
#pragma unroll
    for (int j = 0; j < 4; ++j)
      bfr[sel][j] = *(const bf16x8*)(Bk + j * 1024);
  };

  // per-lane A-frag LDS byte offset (slot is i-invariant: (16i)>>1 ≡ 0 mod 4)
  const int rowA = wm * 64 + l15;
  const int offA = rowA * 64 + (quad ^ ((rowA >> 1) & 3)) * 16;  // bytes

  f32x4 acc[4][4] = {};

  stage(0, 0);
  loadB(0, 0);
#pragma unroll
  for (int kb = 0; kb < NKB; ++kb) {
    if (kb + 1 < NKB) {
      stage(kb + 1, (kb + 1) % 3);
      loadB(kb + 1, (kb + 1) & 1);
      asm volatile("s_waitcnt vmcnt(6)" ::: "memory");  // stage(kb)+B(kb) done
    } else {
      asm volatile("s_waitcnt vmcnt(0)" ::: "memory");
    }
    asm volatile("s_barrier" ::: "memory");             // A tile kb complete

    const char* As = (const char*)bufA[kb % 3] + offA;
    const int s = kb & 1;
#pragma unroll
    for (int i = 0; i < 4; ++i) {
      bf16x8 af = *(const bf16x8*)(As + i * 1024);      // stream A frag i
#pragma unroll
      for (int j = 0; j < 4; ++j)
        acc[i][j] = __builtin_amdgcn_mfma_f32_16x16x32_bf16(
            af, bfr[s][j], acc[i][j], 0, 0, 0);
    }
  }

  // ---- lean epilogue: bare exp2, no masks, shuffle-reduced atomics ----
  float cp[4] = {0.f, 0.f, 0.f, 0.f};
#pragma unroll
  for (int i = 0; i < 4; ++i)
#pragma unroll
    for (int r = 0; r < 4; ++r) {
      float rv = 0.f;
#pragma unroll
      for (int j = 0; j < 4; ++j) {
        float e = exp2f(acc[i][j][r]);
        rv += e;
        cp[j] += e;
      }
      rv += __shfl_xor(rv, 1); rv += __shfl_xor(rv, 2);
      rv += __shfl_xor(rv, 4); rv += __shfl_xor(rv, 8);
      if (l15 == 0)
        atomicAdd(&row_sum[(size_t)b * MP + m0 + wm * 64 + i * 16 + quad * 4 + r], rv);
    }
#pragma unroll
  for (int j = 0; j < 4; ++j) {
    float c = cp[j];
    c += __shfl_xor(c, 16); c += __shfl_xor(c, 32);
    if (quad == 0)
      atomicAdd(&col_sum[(size_t)b * MP + n0 + wn * 64 + j * 16 + l15], c);
  }
  if (mt == nt && wm == wn) {
#pragma unroll
    for (int i = 0; i < 4; ++i)
#pragma unroll
      for (int r = 0; r < 4; ++r)
        if (l15 == quad * 4 + r)
          diag[(size_t)b * MP + m0 + wm * 64 + i * 16 + quad * 4 + r] =
              acc[i][i][r];
  }
}

// ---------------------------------------------------------------------------
// loss = mean over valid of log(rs - pad) + log(cs - pad) - 2*ln2*diag'
// pad = MP - M exact (pad rows/cols contributed exp2(0)=1 each).
// ---------------------------------------------------------------------------
__global__ __launch_bounds__(256)
void finalize(const float* __restrict__ row_sum, const float* __restrict__ col_sum,
              const float* __restrict__ diag, float* __restrict__ out,
              int M, float padf, float inv_total) {
  __shared__ float red[4];
  const int i = blockIdx.x * 256 + threadIdx.x;   // over NB*MP
  const int mm = i % MP;
  float s = 0.f;
  if (mm < M)
    s = __logf(row_sum[i] - padf) + __logf(col_sum[i] - padf) - LN2X2 * diag[i];
#pragma unroll
  for (int o = 1; o < 64; o <<= 1) s += __shfl_xor(s, o);
  const int lane = threadIdx.x & 63, wid = threadIdx.x >> 6;
  if (lane == 0) red[wid] = s;
  __syncthreads();
  if (threadIdx.x == 0)
    atomicAdd(out, (red[0] + red[1] + red[2] + red[3]) * inv_total);
}

extern "C" void kernel_launch(void* const* d_in, const int* in_sizes, int n_in,
                              void* d_out, int out_size, void* d_ws, size_t ws_size,
                              hipStream_t stream) {
  const float* p1 = (const float*)d_in[0];
  const float* p2 = (const float*)d_in[1];
  const int* y1 = (const int*)d_in[2];
  const int* x1 = (const int*)d_in[3];
  const int* y2 = (const int*)d_in[4];
  const int* x2 = (const int*)d_in[5];
  const int M = in_sizes[2];                    // 3540 (<= MP)

  float* row_sum = (float*)d_ws;                // NB*MP
  float* col_sum = row_sum + (size_t)NB * MP;   // NB*MP
  float* diagbuf = col_sum + (size_t)NB * MP;   // NB*MP
  size_t off = (((size_t)3 * NB * MP * sizeof(float)) + 255) & ~(size_t)255;
  u16* des1 = (u16*)((char*)d_ws + off);        // NB*MP*NC bf16, tiled+swizzled
  u16* des2 = des1 + (size_t)NB * MP * NC;

  // zeroing of row/col sums + out folded into gather_kernel (fewer graph nodes)
  // 1-D grid: id%8 == b -> gather writes des[b] on the XCD that reads it
  gather_kernel<<<dim3(2 * NKB * NRB * 8), 256, 0, stream>>>(
      p1, p2, y1, x1, y2, x2, des1, des2, row_sum, (float*)d_out, M);

  mfma_lse<<<dim3(NB * NRB * NRB), 256, 0, stream>>>(des1, des2, row_sum,
                                                     col_sum, diagbuf, M);

  finalize<<<(NB * MP) / 256, 256, 0, stream>>>(row_sum, col_sum, diagbuf,
                                                (float*)d_out, M,
                                                (float)(MP - M),
                                                1.f / (float)(NB * M));
}